// Round 5
// baseline (2162.879 us; speedup 1.0000x reference)
//
#include <hip/hip_runtime.h>
#include <cstddef>

namespace {
constexpr int S = 512;
constexpr int B = 64;
constexpr int H = 768;
constexpr int T = 32;
constexpr int START = 30;
constexpr int END = 31;
}

// ---------------------------------------------------------------------------
// Kernel 1: emissions. emitT[b][s][t] = dot(emb[s,b,:], W[:,t]) + bias[t]
// One wave per s. NO LDS (r4 post-mortem: LDS-pipe-bound at 3 LDS/8 FMA).
// Per thread: 4 tags x 8 rows register tile; A rows reused 8x via L1.
// ---------------------------------------------------------------------------
__global__ __launch_bounds__(64) void emit_gemm(const float* __restrict__ A,
                                                 const float* __restrict__ W,
                                                 const float* __restrict__ bias,
                                                 float* __restrict__ emitT) {
  const int tid = threadIdx.x;
  const int s = blockIdx.x;
  const int t0 = (tid & 7) * 4;   // 4 tags
  const int r0 = (tid >> 3) * 8;  // 8 rows (batches)
  const float* Ablk = A + (size_t)s * B * H;

  float acc[4][8];
#pragma unroll
  for (int t = 0; t < 4; ++t)
#pragma unroll
    for (int k = 0; k < 8; ++k) acc[t][k] = 0.f;

  for (int h = 0; h < H; h += 4) {
    float4 w4[4];
#pragma unroll
    for (int j = 0; j < 4; ++j)
      w4[j] = *(const float4*)(W + (size_t)(h + j) * T + t0);
    float4 a[8];
#pragma unroll
    for (int k = 0; k < 8; ++k)
      a[k] = *(const float4*)(Ablk + (size_t)(r0 + k) * H + h);
#pragma unroll
    for (int k = 0; k < 8; ++k) {
      acc[0][k] = fmaf(a[k].x, w4[0].x, acc[0][k]);
      acc[1][k] = fmaf(a[k].x, w4[0].y, acc[1][k]);
      acc[2][k] = fmaf(a[k].x, w4[0].z, acc[2][k]);
      acc[3][k] = fmaf(a[k].x, w4[0].w, acc[3][k]);
      acc[0][k] = fmaf(a[k].y, w4[1].x, acc[0][k]);
      acc[1][k] = fmaf(a[k].y, w4[1].y, acc[1][k]);
      acc[2][k] = fmaf(a[k].y, w4[1].z, acc[2][k]);
      acc[3][k] = fmaf(a[k].y, w4[1].w, acc[3][k]);
      acc[0][k] = fmaf(a[k].z, w4[2].x, acc[0][k]);
      acc[1][k] = fmaf(a[k].z, w4[2].y, acc[1][k]);
      acc[2][k] = fmaf(a[k].z, w4[2].z, acc[2][k]);
      acc[3][k] = fmaf(a[k].z, w4[2].w, acc[3][k]);
      acc[0][k] = fmaf(a[k].w, w4[3].x, acc[0][k]);
      acc[1][k] = fmaf(a[k].w, w4[3].y, acc[1][k]);
      acc[2][k] = fmaf(a[k].w, w4[3].z, acc[2][k]);
      acc[3][k] = fmaf(a[k].w, w4[3].w, acc[3][k]);
    }
  }
  const float4 bb = *(const float4*)(bias + t0);
#pragma unroll
  for (int k = 0; k < 8; ++k) {
    float4 o;
    o.x = acc[0][k] + bb.x;
    o.y = acc[1][k] + bb.y;
    o.z = acc[2][k] + bb.z;
    o.w = acc[3][k] + bb.w;
    *(float4*)(emitT + ((size_t)(r0 + k) * S + s) * T + t0) = o;
  }
}

// ---------------------------------------------------------------------------
// Kernel 2: CRF scan. 128 blocks x 64 threads (one wave each).
// blocks 0..63: alpha (scaled-prob domain, r3/r4-proven math) + gold -> nll.
// blocks 64..127: viterbi (log domain) + pointer-doubling backtrace.
// dp vector in LDS; EVERY lane reduces over all 32 prevs itself via 8
// broadcast ds_read_b128 (same addr across lanes = conflict-free) -- no
// shfl/bpermute anywhere on the step chain (r4 post-mortem). Lanes 0..31
// write dp. Wave-synchronous (no barriers in loop); fences pin LDS order.
// ---------------------------------------------------------------------------
__global__ __launch_bounds__(64) void crf_scan(const float* __restrict__ emitT,
                                               const int* __restrict__ labels,
                                               const float* __restrict__ trans,
                                               float* __restrict__ out) {
  __shared__ __align__(16) float dpL[T];
  __shared__ unsigned char bp[S * T];   // backpointers (viterbi)
  __shared__ unsigned char jA[S * T];   // jump table B2 then B8
  __shared__ unsigned char jB[S * T];   // jump table B4
  __shared__ unsigned char pathb[S];
  __shared__ int anch[64];

  const int lane = threadIdx.x;
  const int b = blockIdx.x & 63;
  const bool is_vit = blockIdx.x >= 64;
  const int cur = lane & 31;
  const int h = lane >> 5;

  float tr[32];  // full trans row for this cur
#pragma unroll
  for (int j = 0; j < 8; ++j) {
    float4 v = *(const float4*)(trans + cur * T + 4 * j);
    tr[4 * j + 0] = v.x; tr[4 * j + 1] = v.y;
    tr[4 * j + 2] = v.z; tr[4 * j + 3] = v.w;
  }

  const float* ebase = emitT + (size_t)b * (S * T);
  const float* eb = ebase + cur;
  const float e0 = eb[0];

  if (!is_vit) {
    // ================= alpha: scaled-probability domain =================
    // dp_s[cur] = L + log(p). raw = sum_prev etr*p; p' = raw*exp(e)/sigma;
    // L += log(sigma); sigma = lagged readfirstlane(raw).
    float etr[32];
#pragma unroll
    for (int i = 0; i < 32; ++i) etr[i] = __expf(tr[i]);

    float p = __expf(tr[START] + e0);  // exact: step-0 lse = trS + e0
    float L = 0.f;
    float sprev =
        __int_as_float(__builtin_amdgcn_readfirstlane(__float_as_int(p)));
    if (h == 0) dpL[cur] = p;
    asm volatile("" ::: "memory");

    float q1 = eb[2 * T], q2 = eb[3 * T], q3 = eb[4 * T];
    float exCur = __expf(eb[1 * T]);

#pragma unroll 4
    for (int s = 1; s < S; ++s) {
      asm volatile("" ::: "memory");
      float4 d[8];
#pragma unroll
      for (int j = 0; j < 8; ++j) d[j] = *(const float4*)(&dpL[4 * j]);
      const float mult = exCur / sprev;  // off chain (sprev lagged)
      L += __logf(sprev);                // off chain
      float pr[32];
#pragma unroll
      for (int j = 0; j < 8; ++j) {
        pr[4 * j + 0] = etr[4 * j + 0] * d[j].x;
        pr[4 * j + 1] = etr[4 * j + 1] * d[j].y;
        pr[4 * j + 2] = etr[4 * j + 2] * d[j].z;
        pr[4 * j + 3] = etr[4 * j + 3] * d[j].w;
      }
#pragma unroll
      for (int i = 0; i < 16; ++i) pr[i] = pr[2 * i] + pr[2 * i + 1];
#pragma unroll
      for (int i = 0; i < 8; ++i) pr[i] = pr[2 * i] + pr[2 * i + 1];
#pragma unroll
      for (int i = 0; i < 4; ++i) pr[i] = pr[2 * i] + pr[2 * i + 1];
      const float raw = (pr[0] + pr[1]) + (pr[2] + pr[3]);
      p = raw * mult;
      sprev =
          __int_as_float(__builtin_amdgcn_readfirstlane(__float_as_int(raw)));
      if (h == 0) dpL[cur] = p;
      asm volatile("" ::: "memory");
      const float nq = eb[((s + 4) & (S - 1)) * T];
      const float exN = __expf(q1);
      q1 = q2; q2 = q3; q3 = nq;
      exCur = exN;
    }

    // gold path score (off the latency chain)
    float g = 0.f;
    for (int s = lane; s < S; s += 64) {
      const int c = labels[s * B + b];
      const int pl = (s == 0) ? START : labels[(s - 1) * B + b];
      g += trans[c * T + pl] + ebase[s * T + c];
    }
    if (lane == 63) g += trans[END * T + labels[(S - 1) * B + b]];

    // epilogue: logsumexp over tags of (L + log p) + trans[end]
    const float dpf = L + __logf(p);  // -inf for START (p==0): harmless
    const float v = (lane < T) ? dpf + trans[END * T + lane] : -3.0e38f;
    float mx = v;
#pragma unroll
    for (int o = 32; o >= 1; o >>= 1) mx = fmaxf(mx, __shfl_xor(mx, o));
    float sm = (lane < T) ? __expf(v - mx) : 0.f;
#pragma unroll
    for (int o = 32; o >= 1; o >>= 1) sm += __shfl_xor(sm, o);
    const float lp = mx + __logf(sm);
#pragma unroll
    for (int o = 32; o >= 1; o >>= 1) g += __shfl_xor(g, o);
    if (lane == 0) out[b] = lp - g;
  } else {
    // ================= viterbi: log domain =================
    float p = tr[START] + e0;  // step-0 max collapses to prev=START
    if (lane < 32) bp[cur] = (unsigned char)START;
    if (h == 0) dpL[cur] = p;
    asm volatile("" ::: "memory");

    float q0 = eb[1 * T], q1 = eb[2 * T], q2 = eb[3 * T], q3 = eb[4 * T];

#pragma unroll 4
    for (int s = 1; s < S; ++s) {
      float tq[32];
#pragma unroll
      for (int i = 0; i < 32; ++i) tq[i] = tr[i] + q0;  // issues under LDS wait
      asm volatile("" ::: "memory");
      float4 d[8];
#pragma unroll
      for (int j = 0; j < 8; ++j) d[j] = *(const float4*)(&dpL[4 * j]);
      float v[32];
#pragma unroll
      for (int j = 0; j < 8; ++j) {
        v[4 * j + 0] = tq[4 * j + 0] + d[j].x;  // (tr+e)+dp: ref add order
        v[4 * j + 1] = tq[4 * j + 1] + d[j].y;
        v[4 * j + 2] = tq[4 * j + 2] + d[j].z;
        v[4 * j + 3] = tq[4 * j + 3] + d[j].w;
      }
      float mv[16]; int mi[16];
#pragma unroll
      for (int i = 0; i < 16; ++i) {
        const bool r = v[2 * i + 1] > v[2 * i];  // strict: ties -> lower idx
        mv[i] = r ? v[2 * i + 1] : v[2 * i];
        mi[i] = r ? 2 * i + 1 : 2 * i;
      }
#pragma unroll
      for (int i = 0; i < 8; ++i) {
        const bool r = mv[2 * i + 1] > mv[2 * i];
        mv[i] = r ? mv[2 * i + 1] : mv[2 * i];
        mi[i] = r ? mi[2 * i + 1] : mi[2 * i];
      }
#pragma unroll
      for (int i = 0; i < 4; ++i) {
        const bool r = mv[2 * i + 1] > mv[2 * i];
        mv[i] = r ? mv[2 * i + 1] : mv[2 * i];
        mi[i] = r ? mi[2 * i + 1] : mi[2 * i];
      }
#pragma unroll
      for (int i = 0; i < 2; ++i) {
        const bool r = mv[2 * i + 1] > mv[2 * i];
        mv[i] = r ? mv[2 * i + 1] : mv[2 * i];
        mi[i] = r ? mi[2 * i + 1] : mi[2 * i];
      }
      const bool r = mv[1] > mv[0];
      p = r ? mv[1] : mv[0];
      const int arg = r ? mi[1] : mi[0];
      if (h == 0) {
        dpL[cur] = p;
        bp[s * T + cur] = (unsigned char)arg;
      }
      asm volatile("" ::: "memory");
      const float nq = eb[((s + 4) & (S - 1)) * T];
      q0 = q1; q1 = q2; q2 = q3; q3 = nq;
    }

    // final argmax over tags (first-max tie-break)
    float v = (lane < T) ? p + trans[END * T + lane] : -3.0e38f;
    int a = lane;
#pragma unroll
    for (int o = 32; o >= 1; o >>= 1) {
      const float ov = __shfl_xor(v, o);
      const int oa = __shfl_xor(a, o);
      if (ov > v || (ov == v && oa < a)) { v = ov; a = oa; }
    }
    if (lane == 0) out[64 + 32768 + b] = v;
    __syncthreads();

    // ---- pointer-doubling backtrace (r4-validated) ----
    for (int idx = lane; idx < S * T; idx += 64) {
      const int s = idx >> 5;
      if (s >= 1) jA[idx] = bp[(s - 1) * T + bp[idx]];
    }
    __syncthreads();
    for (int idx = lane; idx < S * T; idx += 64) {
      const int s = idx >> 5;
      if (s >= 3) jB[idx] = jA[(s - 2) * T + jA[idx]];
    }
    __syncthreads();
    for (int idx = lane; idx < S * T; idx += 64) {
      const int s = idx >> 5;
      if (s >= 7) jA[idx] = jB[(s - 4) * T + jB[idx]];
    }
    __syncthreads();
    if (lane == 0) {
      int t = a;
      anch[0] = t;
      for (int j = 1; j < 64; ++j) {
        t = jA[(511 - 8 * (j - 1)) * T + t];  // t_{s-8} = B8[s][t_s]
        anch[j] = t;
      }
    }
    __syncthreads();
    {
      int t = anch[lane];
      const int s0 = 511 - 8 * lane;
      pathb[s0] = (unsigned char)t;
#pragma unroll
      for (int k = 1; k < 8; ++k) {
        t = bp[(s0 - k + 1) * T + t];
        pathb[s0 - k] = (unsigned char)t;
      }
    }
    __syncthreads();
    for (int i = lane; i < S; i += 64) out[64 + b * S + i] = (float)pathb[i];
  }
}

// ---------------------------------------------------------------------------
extern "C" void kernel_launch(void* const* d_in, const int* in_sizes, int n_in,
                              void* d_out, int out_size, void* d_ws,
                              size_t ws_size, hipStream_t stream) {
  const float* emb = (const float*)d_in[0];
  const int* labels = (const int*)d_in[1];
  const float* W = (const float*)d_in[2];
  const float* bias = (const float*)d_in[3];
  const float* trans = (const float*)d_in[4];
  float* out = (float*)d_out;
  float* emitT = (float*)d_ws;  // 4 MiB scratch

  emit_gemm<<<S, 64, 0, stream>>>(emb, W, bias, emitT);
  crf_scan<<<2 * B, 64, 0, stream>>>(emitT, labels, trans, out);
}

// Round 6
// 345.679 us; speedup vs baseline: 6.2569x; 6.2569x over previous
//
#include <hip/hip_runtime.h>
#include <cstddef>

namespace {
constexpr int S = 512;
constexpr int B = 64;
constexpr int H = 768;
constexpr int T = 32;
constexpr int START = 30;
constexpr int END = 31;
constexpr int CH = 32;   // chunks
constexpr int CL = 16;   // own steps per chunk (warmup = previous chunk)
}

__device__ __forceinline__ float bf2f(unsigned short u) {
  return __uint_as_float(((unsigned int)u) << 16);
}
__device__ __forceinline__ unsigned short f2bf(float x) {  // RNE
  unsigned int u = __float_as_uint(x);
  unsigned int r = (u + 0x7FFF + ((u >> 16) & 1)) >> 16;
  return (unsigned short)r;
}

// ---------------------------------------------------------------------------
// Kernel 1: emissions -> bf16, batch-major emitb[b][s][t].
// Thread tile 4 rows x 4 cols, K by float4. No LDS (r4/r5 lesson: LDS-pipe
// and L1 both choke wide-reuse patterns; small tile + 1024 waves instead).
// ---------------------------------------------------------------------------
__global__ __launch_bounds__(256) void emit_gemm(const float* __restrict__ A,
                                                 const float* __restrict__ W,
                                                 const float* __restrict__ bias,
                                                 unsigned short* __restrict__ emitb) {
  const int tid = threadIdx.x;
  const int cg = tid & 7, rg = tid >> 3;
  const int c0 = cg * 4;
  const int r0 = blockIdx.x * 128 + rg * 4;   // 256 blocks x 128 rows
  float acc[4][4] = {};
  const float* a0 = A + (size_t)r0 * H;
#pragma unroll 2
  for (int hh = 0; hh < H; hh += 4) {
    float4 wv[4];
#pragma unroll
    for (int k = 0; k < 4; ++k)
      wv[k] = *(const float4*)(W + (size_t)(hh + k) * T + c0);
    float4 av[4];
#pragma unroll
    for (int i = 0; i < 4; ++i)
      av[i] = *(const float4*)(a0 + (size_t)i * H + hh);
#pragma unroll
    for (int i = 0; i < 4; ++i) {
      const float* ap = &av[i].x;
#pragma unroll
      for (int k = 0; k < 4; ++k) {
        const float aa = ap[k];
        const float* wp = &wv[k].x;
#pragma unroll
        for (int j = 0; j < 4; ++j) acc[i][j] = fmaf(aa, wp[j], acc[i][j]);
      }
    }
  }
  const float4 bb4 = *(const float4*)(bias + c0);
  const float* bb = &bb4.x;
#pragma unroll
  for (int i = 0; i < 4; ++i) {
    const int r = r0 + i, s = r >> 6, b = r & 63;
    ushort4 o;
    o.x = f2bf(acc[i][0] + bb[0]);
    o.y = f2bf(acc[i][1] + bb[1]);
    o.z = f2bf(acc[i][2] + bb[2]);
    o.w = f2bf(acc[i][3] + bb[3]);
    *(ushort4*)(emitb + (size_t)b * S * T + s * T + c0) = o;
  }
}

// ---------------------------------------------------------------------------
// r2-verbatim step functions (the only measured-acceptable inner loop).
// Lane = (cur = l&31, half = l>>5); 16 prevs/lane; shfl_xor(32) combine.
// ---------------------------------------------------------------------------
__device__ __forceinline__ float astep(float e, const float* tr, float* dp,
                                       int cur, int h) {
  asm volatile("" ::: "memory");
  const float* dh = dp + h * 16;
  float v[16];
#pragma unroll
  for (int j = 0; j < 4; ++j) {
    float4 d = *(const float4*)(dh + 4 * j);
    v[4 * j + 0] = (tr[4 * j + 0] + e) + d.x;
    v[4 * j + 1] = (tr[4 * j + 1] + e) + d.y;
    v[4 * j + 2] = (tr[4 * j + 2] + e) + d.z;
    v[4 * j + 3] = (tr[4 * j + 3] + e) + d.w;
  }
  float m = -3.0e38f;
#pragma unroll
  for (int i = 0; i < 16; ++i) m = fmaxf(m, v[i]);
  m = fmaxf(m, __shfl_xor(m, 32));
  float sum = 0.f;
#pragma unroll
  for (int i = 0; i < 16; ++i) sum += __expf(v[i] - m);
  sum += __shfl_xor(sum, 32);
  const float nd = m + __logf(sum);
  if (h == 0) dp[cur] = nd;
  asm volatile("" ::: "memory");
  return nd;
}

__device__ __forceinline__ void vstep(float e, const float* tr, float* dp,
                                      int cur, int h, float& obest, int& oarg) {
  asm volatile("" ::: "memory");
  const float* dh = dp + h * 16;
  float best = -3.0e38f;
  int arg = 0;
#pragma unroll
  for (int j = 0; j < 4; ++j) {
    float4 d = *(const float4*)(dh + 4 * j);
    float vv[4] = {(tr[4 * j + 0] + e) + d.x, (tr[4 * j + 1] + e) + d.y,
                   (tr[4 * j + 2] + e) + d.z, (tr[4 * j + 3] + e) + d.w};
#pragma unroll
    for (int k = 0; k < 4; ++k) {
      const int p = h * 16 + 4 * j + k;
      if (vv[k] > best) { best = vv[k]; arg = p; }  // first-max ties
    }
  }
  const float ob = __shfl_xor(best, 32);
  const int oa = __shfl_xor(arg, 32);
  if (ob > best || (ob == best && oa < arg)) { best = ob; arg = oa; }
  if (h == 0) dp[cur] = best;
  asm volatile("" ::: "memory");
  obest = best;
  oarg = arg;
}

// ---------------------------------------------------------------------------
// Kernel 2: chunked scan. Grid = 2 modes x 32 chunks x 64 batches = 4096
// blocks x 64 threads (16 waves/CU). Chunk c: warm-start dp=0 at s=16c-16
// (chunk 0: exact init), run through s=16c+15. Offsets reconciled by
// telescoping on dp[0]: a_c = entry value (s=16c-1), b_c = exit (s=16c+15).
// Viterbi chunks write bp rows for their own 16 steps to global.
// ---------------------------------------------------------------------------
__global__ __launch_bounds__(64) void crf_chunk(
    const unsigned short* __restrict__ emitb, const float* __restrict__ trans,
    float* __restrict__ aA, float* __restrict__ bA, float* __restrict__ finA,
    float* __restrict__ aV, float* __restrict__ bV, float* __restrict__ finV,
    int* __restrict__ tagV, unsigned char* __restrict__ bpG) {
  __shared__ __align__(16) float dpL[T];
  const int bid = blockIdx.x;
  const int lane = threadIdx.x;
  const int cur = lane & 31;
  const int h = lane >> 5;
  const int gbase = h * 16;
  const int mode = bid >> 11;       // 0=alpha, 1=viterbi
  const int c = (bid >> 6) & 31;
  const int b = bid & 63;

  float tr[16];
#pragma unroll
  for (int j = 0; j < 4; ++j) {
    float4 v = *(const float4*)(trans + cur * T + gbase + 4 * j);
    tr[4 * j + 0] = v.x; tr[4 * j + 1] = v.y;
    tr[4 * j + 2] = v.z; tr[4 * j + 3] = v.w;
  }

  const unsigned short* eb = emitb + (size_t)b * S * T + cur;
  const int own = c * CL;
  const int w_begin = (c == 0) ? 0 : own - CL;
  const int send = own + CL;

  if (lane < T)
    dpL[cur] = (c == 0) ? ((cur == START) ? 0.f : -100000.f) : 0.f;
  asm volatile("" ::: "memory");

  // emission prefetch pipeline, distance 4, clamped to window
  unsigned short q0 = eb[w_begin * T];
  unsigned short q1 = eb[(w_begin + 1 < send ? w_begin + 1 : send - 1) * T];
  unsigned short q2 = eb[(w_begin + 2 < send ? w_begin + 2 : send - 1) * T];
  unsigned short q3 = eb[(w_begin + 3 < send ? w_begin + 3 : send - 1) * T];

  float aVal = 0.f, bVal = 0.f;
  if (mode == 0) {
    for (int s = w_begin; s < send; ++s) {
      const int np = (s + 4 < send) ? s + 4 : send - 1;
      const unsigned short nq = eb[np * T];
      const float nd = astep(bf2f(q0), tr, dpL, cur, h);
      if (lane == 0) {
        if (s == own - 1) aVal = nd;
        if (s == send - 1) bVal = nd;
      }
      q0 = q1; q1 = q2; q2 = q3; q3 = nq;
    }
    if (lane == 0) { aA[b * CH + c] = aVal; bA[b * CH + c] = bVal; }
    if (c == CH - 1) {
      asm volatile("" ::: "memory");
      const float v = (lane < T) ? dpL[lane] + trans[END * T + lane] : -3.0e38f;
      float mx = v;
#pragma unroll
      for (int o = 32; o >= 1; o >>= 1) mx = fmaxf(mx, __shfl_xor(mx, o));
      float sm = (lane < T) ? __expf(v - mx) : 0.f;
#pragma unroll
      for (int o = 32; o >= 1; o >>= 1) sm += __shfl_xor(sm, o);
      if (lane == 0) finA[b] = mx + __logf(sm);
    }
  } else {
    unsigned char* bpb = bpG + (size_t)b * S * T;
    for (int s = w_begin; s < send; ++s) {
      const int np = (s + 4 < send) ? s + 4 : send - 1;
      const unsigned short nq = eb[np * T];
      float best; int arg;
      vstep(bf2f(q0), tr, dpL, cur, h, best, arg);
      if (h == 0 && s >= own) bpb[s * T + cur] = (unsigned char)arg;
      if (lane == 0) {
        if (s == own - 1) aVal = best;
        if (s == send - 1) bVal = best;
      }
      q0 = q1; q1 = q2; q2 = q3; q3 = nq;
    }
    if (lane == 0) { aV[b * CH + c] = aVal; bV[b * CH + c] = bVal; }
    if (c == CH - 1) {
      asm volatile("" ::: "memory");
      float v = (lane < T) ? dpL[lane] + trans[END * T + lane] : -3.0e38f;
      int a = lane;
#pragma unroll
      for (int o = 32; o >= 1; o >>= 1) {
        const float ov = __shfl_xor(v, o);
        const int oa = __shfl_xor(a, o);
        if (ov > v || (ov == v && oa < a)) { v = ov; a = oa; }
      }
      if (lane == 0) { finV[b] = v; tagV[b] = a; }
    }
  }
}

// ---------------------------------------------------------------------------
// Kernel 3: per-batch assembly. Gold score, delta telescoping, outputs,
// and the r4-proven pointer-doubling backtrace from global bp.
// ---------------------------------------------------------------------------
__global__ __launch_bounds__(64) void crf_final(
    const unsigned short* __restrict__ emitb, const int* __restrict__ labels,
    const float* __restrict__ trans,
    const float* __restrict__ aA, const float* __restrict__ bA,
    const float* __restrict__ finA,
    const float* __restrict__ aV, const float* __restrict__ bV,
    const float* __restrict__ finV, const int* __restrict__ tagV,
    const unsigned char* __restrict__ bpG, float* __restrict__ out) {
  __shared__ __align__(16) unsigned char bp[S * T];
  __shared__ unsigned char jA[S * T];
  __shared__ unsigned char jB[S * T];
  __shared__ unsigned char pathb[S];
  __shared__ int anch[64];
  const int lane = threadIdx.x;
  const int b = blockIdx.x;

  // stage bp into LDS (coalesced int4)
  {
    const int4* src = (const int4*)(bpG + (size_t)b * S * T);
    int4* dst = (int4*)bp;
    for (int i = lane; i < S * T / 16; i += 64) dst[i] = src[i];
  }

  // gold path score
  float g = 0.f;
  for (int s = lane; s < S; s += 64) {
    const int cl = labels[s * B + b];
    const int pl = (s == 0) ? START : labels[(s - 1) * B + b];
    g += trans[cl * T + pl] + bf2f(emitb[(size_t)b * S * T + s * T + cl]);
  }
  if (lane == 63) g += trans[END * T + labels[(S - 1) * B + b]];
#pragma unroll
  for (int o = 32; o >= 1; o >>= 1) g += __shfl_xor(g, o);

  // delta telescoping: delta = sum_{c=1..31} (b_{c-1} - a_c)
  float tb = 0.f, ta = 0.f, vb = 0.f, va = 0.f;
  if (lane < CH - 1) tb = bA[b * CH + lane];
  if (lane >= 1 && lane < CH) ta = aA[b * CH + lane];
  if (lane < CH - 1) vb = bV[b * CH + lane];
  if (lane >= 1 && lane < CH) va = aV[b * CH + lane];
  float dA = tb - ta, dV = vb - va;
#pragma unroll
  for (int o = 32; o >= 1; o >>= 1) {
    dA += __shfl_xor(dA, o);
    dV += __shfl_xor(dV, o);
  }
  if (lane == 0) {
    out[b] = (finA[b] + dA) - g;               // nll
    out[64 + 32768 + b] = finV[b] + dV;        // best score
  }
  __syncthreads();

  // pointer-doubling backtrace (r4-validated)
  for (int idx = lane; idx < S * T; idx += 64) {
    const int s = idx >> 5;
    if (s >= 1) jA[idx] = bp[(s - 1) * T + bp[idx]];
  }
  __syncthreads();
  for (int idx = lane; idx < S * T; idx += 64) {
    const int s = idx >> 5;
    if (s >= 3) jB[idx] = jA[(s - 2) * T + jA[idx]];
  }
  __syncthreads();
  for (int idx = lane; idx < S * T; idx += 64) {
    const int s = idx >> 5;
    if (s >= 7) jA[idx] = jB[(s - 4) * T + jB[idx]];
  }
  __syncthreads();
  if (lane == 0) {
    int t = tagV[b];
    anch[0] = t;
    for (int j = 1; j < 64; ++j) {
      t = jA[(511 - 8 * (j - 1)) * T + t];
      anch[j] = t;
    }
  }
  __syncthreads();
  {
    int t = anch[lane];
    const int s0 = 511 - 8 * lane;
    pathb[s0] = (unsigned char)t;
#pragma unroll
    for (int k = 1; k < 8; ++k) {
      t = bp[(s0 - k + 1) * T + t];
      pathb[s0 - k] = (unsigned char)t;
    }
  }
  __syncthreads();
  for (int i = lane; i < S; i += 64) out[64 + b * S + i] = (float)pathb[i];
}

// ---------------------------------------------------------------------------
extern "C" void kernel_launch(void* const* d_in, const int* in_sizes, int n_in,
                              void* d_out, int out_size, void* d_ws,
                              size_t ws_size, hipStream_t stream) {
  const float* emb = (const float*)d_in[0];
  const int* labels = (const int*)d_in[1];
  const float* W = (const float*)d_in[2];
  const float* bias = (const float*)d_in[3];
  const float* trans = (const float*)d_in[4];
  float* out = (float*)d_out;

  // ws layout (3.15 MB total, ws_size known >= 4 MiB from round 2):
  char* p = (char*)d_ws;
  unsigned short* emitb = (unsigned short*)p;           // 2 MiB
  p += (size_t)B * S * T * sizeof(unsigned short);
  unsigned char* bpG = (unsigned char*)p;               // 1 MiB
  p += (size_t)B * S * T;
  float* aA = (float*)p; p += B * CH * sizeof(float);
  float* bA = (float*)p; p += B * CH * sizeof(float);
  float* aV = (float*)p; p += B * CH * sizeof(float);
  float* bV = (float*)p; p += B * CH * sizeof(float);
  float* finA = (float*)p; p += B * sizeof(float);
  float* finV = (float*)p; p += B * sizeof(float);
  int* tagV = (int*)p;

  emit_gemm<<<256, 256, 0, stream>>>(emb, W, bias, emitb);
  crf_chunk<<<2 * CH * B, 64, 0, stream>>>(emitb, trans, aA, bA, finA, aV, bV,
                                           finV, tagV, bpG);
  crf_final<<<B, 64, 0, stream>>>(emitb, labels, trans, aA, bA, finA, aV, bV,
                                  finV, tagV, bpG, out);
}

// Round 7
// 214.246 us; speedup vs baseline: 10.0953x; 1.6135x over previous
//
#include <hip/hip_runtime.h>
#include <cstddef>

namespace {
constexpr int S = 512;
constexpr int B = 64;
constexpr int H = 768;
constexpr int T = 32;
constexpr int START = 30;
constexpr int END = 31;
constexpr int CH = 32;   // chunks
constexpr int CL = 16;   // own steps per chunk (warmup = previous chunk)
}

typedef short bf16x8 __attribute__((ext_vector_type(8)));
typedef float f32x4 __attribute__((ext_vector_type(4)));

__device__ __forceinline__ float bf2f(unsigned short u) {
  return __uint_as_float(((unsigned int)u) << 16);
}
__device__ __forceinline__ unsigned short f2bf(float x) {  // RNE
  unsigned int u = __float_as_uint(x);
  unsigned int r = (u + 0x7FFF + ((u >> 16) & 1)) >> 16;
  return (unsigned short)r;
}

// ---------------------------------------------------------------------------
// Kernel 0: pack W into MFMA B-fragment order (bf16).
// frag index tau = kk*128 + eta*64 + lane; element j: B[k=kk*32+quad*8+j]
// [n=eta*16+(lane&15)]  (16x16x32 B-layout, m120-verified).
// ---------------------------------------------------------------------------
__global__ __launch_bounds__(256) void wprep(const float* __restrict__ W,
                                             unsigned short* __restrict__ wfrag) {
  const int tau = blockIdx.x * 256 + threadIdx.x;  // 0..3071
  if (tau >= 24 * 2 * 64) return;
  const int kk = tau >> 7;
  const int eta = (tau >> 6) & 1;
  const int lane = tau & 63;
  const int quad = lane >> 4, m = lane & 15;
  unsigned int pk[4];
#pragma unroll
  for (int jj = 0; jj < 4; ++jj) {
    const unsigned short lo =
        f2bf(W[(kk * 32 + quad * 8 + 2 * jj) * T + eta * 16 + m]);
    const unsigned short hi =
        f2bf(W[(kk * 32 + quad * 8 + 2 * jj + 1) * T + eta * 16 + m]);
    pk[jj] = (unsigned int)lo | ((unsigned int)hi << 16);
  }
  uint4* dst = (uint4*)(wfrag + (size_t)tau * 8);
  *dst = make_uint4(pk[0], pk[1], pk[2], pk[3]);
}

// ---------------------------------------------------------------------------
// Kernel 1: emissions via MFMA 16x16x32 bf16. One wave = 16 rows (one s,
// batches b0..b0+15) x 32 tags. A-fragments straight from global fp32
// (A[m=lane&15][k=quad*8+j]), 4-step prefetch; B-fragments from wfrag
// (1 coalesced b128, L2-hot). C/D: col=lane&15, row=quad*4+reg (m89).
// ---------------------------------------------------------------------------
__global__ __launch_bounds__(256) void emit_mfma(const float* __restrict__ A,
                                                 const unsigned short* __restrict__ wfrag,
                                                 const float* __restrict__ bias,
                                                 unsigned short* __restrict__ emitb) {
  const int tid = threadIdx.x;
  const int wave = tid >> 6, lane = tid & 63;
  const int tile = blockIdx.x * 4 + wave;  // 0..2047
  const int r0 = tile * 16;
  const int m = lane & 15, quad = lane >> 4;
  const float* arow = A + (size_t)(r0 + m) * H + quad * 8;

  f32x4 acc0 = {0.f, 0.f, 0.f, 0.f}, acc1 = {0.f, 0.f, 0.f, 0.f};

  float4 pa[4][2];
#pragma unroll
  for (int d = 0; d < 4; ++d) {
    pa[d][0] = *(const float4*)(arow + d * 32);
    pa[d][1] = *(const float4*)(arow + d * 32 + 4);
  }
  const bf16x8* wf = (const bf16x8*)wfrag;  // [24][2][64]
  bf16x8 pb[2][2];
#pragma unroll
  for (int d = 0; d < 2; ++d) {
    pb[d][0] = wf[(d * 2 + 0) * 64 + lane];
    pb[d][1] = wf[(d * 2 + 1) * 64 + lane];
  }

#pragma unroll
  for (int kk = 0; kk < 24; ++kk) {
    const float4 a0 = pa[kk & 3][0], a1 = pa[kk & 3][1];
    if (kk + 4 < 24) {
      pa[kk & 3][0] = *(const float4*)(arow + (kk + 4) * 32);
      pa[kk & 3][1] = *(const float4*)(arow + (kk + 4) * 32 + 4);
    }
    const bf16x8 b0 = pb[kk & 1][0], b1 = pb[kk & 1][1];
    if (kk + 2 < 24) {
      pb[kk & 1][0] = wf[((kk + 2) * 2 + 0) * 64 + lane];
      pb[kk & 1][1] = wf[((kk + 2) * 2 + 1) * 64 + lane];
    }
    bf16x8 af;
    af[0] = (short)f2bf(a0.x);
    af[1] = (short)f2bf(a0.y);
    af[2] = (short)f2bf(a0.z);
    af[3] = (short)f2bf(a0.w);
    af[4] = (short)f2bf(a1.x);
    af[5] = (short)f2bf(a1.y);
    af[6] = (short)f2bf(a1.z);
    af[7] = (short)f2bf(a1.w);
    acc0 = __builtin_amdgcn_mfma_f32_16x16x32_bf16(af, b0, acc0, 0, 0, 0);
    acc1 = __builtin_amdgcn_mfma_f32_16x16x32_bf16(af, b1, acc1, 0, 0, 0);
  }

  // epilogue: rows of tile share s; b = (r0&63) + quad*4 + reg; tag = eta*16+m
  const int s = r0 >> 6, b0r = r0 & 63;
  const float bia0 = bias[m], bia1 = bias[16 + m];
#pragma unroll
  for (int reg = 0; reg < 4; ++reg) {
    const int b = b0r + quad * 4 + reg;
    unsigned short* o = emitb + (size_t)b * (S * T) + s * T;
    o[m] = f2bf(acc0[reg] + bia0);
    o[16 + m] = f2bf(acc1[reg] + bia1);
  }
}

// ---------------------------------------------------------------------------
// r2-verbatim step functions (the only measured-acceptable inner loop).
// ---------------------------------------------------------------------------
__device__ __forceinline__ float astep(float e, const float* tr, float* dp,
                                       int cur, int h) {
  asm volatile("" ::: "memory");
  const float* dh = dp + h * 16;
  float v[16];
#pragma unroll
  for (int j = 0; j < 4; ++j) {
    float4 d = *(const float4*)(dh + 4 * j);
    v[4 * j + 0] = (tr[4 * j + 0] + e) + d.x;
    v[4 * j + 1] = (tr[4 * j + 1] + e) + d.y;
    v[4 * j + 2] = (tr[4 * j + 2] + e) + d.z;
    v[4 * j + 3] = (tr[4 * j + 3] + e) + d.w;
  }
  float m = -3.0e38f;
#pragma unroll
  for (int i = 0; i < 16; ++i) m = fmaxf(m, v[i]);
  m = fmaxf(m, __shfl_xor(m, 32));
  float sum = 0.f;
#pragma unroll
  for (int i = 0; i < 16; ++i) sum += __expf(v[i] - m);
  sum += __shfl_xor(sum, 32);
  const float nd = m + __logf(sum);
  if (h == 0) dp[cur] = nd;
  asm volatile("" ::: "memory");
  return nd;
}

__device__ __forceinline__ void vstep(float e, const float* tr, float* dp,
                                      int cur, int h, float& obest, int& oarg) {
  asm volatile("" ::: "memory");
  const float* dh = dp + h * 16;
  float best = -3.0e38f;
  int arg = 0;
#pragma unroll
  for (int j = 0; j < 4; ++j) {
    float4 d = *(const float4*)(dh + 4 * j);
    float vv[4] = {(tr[4 * j + 0] + e) + d.x, (tr[4 * j + 1] + e) + d.y,
                   (tr[4 * j + 2] + e) + d.z, (tr[4 * j + 3] + e) + d.w};
#pragma unroll
    for (int k = 0; k < 4; ++k) {
      const int p = h * 16 + 4 * j + k;
      if (vv[k] > best) { best = vv[k]; arg = p; }  // first-max ties
    }
  }
  const float ob = __shfl_xor(best, 32);
  const int oa = __shfl_xor(arg, 32);
  if (ob > best || (ob == best && oa < arg)) { best = ob; arg = oa; }
  if (h == 0) dp[cur] = best;
  asm volatile("" ::: "memory");
  obest = best;
  oarg = arg;
}

// ---------------------------------------------------------------------------
// Kernel 2: chunked scan (r6-verbatim). 2 modes x 32 chunks x 64 batches.
// ---------------------------------------------------------------------------
__global__ __launch_bounds__(64) void crf_chunk(
    const unsigned short* __restrict__ emitb, const float* __restrict__ trans,
    float* __restrict__ aA, float* __restrict__ bA, float* __restrict__ finA,
    float* __restrict__ aV, float* __restrict__ bV, float* __restrict__ finV,
    int* __restrict__ tagV, unsigned char* __restrict__ bpG) {
  __shared__ __align__(16) float dpL[T];
  const int bid = blockIdx.x;
  const int lane = threadIdx.x;
  const int cur = lane & 31;
  const int h = lane >> 5;
  const int gbase = h * 16;
  const int mode = bid >> 11;  // 0=alpha, 1=viterbi
  const int c = (bid >> 6) & 31;
  const int b = bid & 63;

  float tr[16];
#pragma unroll
  for (int j = 0; j < 4; ++j) {
    float4 v = *(const float4*)(trans + cur * T + gbase + 4 * j);
    tr[4 * j + 0] = v.x; tr[4 * j + 1] = v.y;
    tr[4 * j + 2] = v.z; tr[4 * j + 3] = v.w;
  }

  const unsigned short* eb = emitb + (size_t)b * S * T + cur;
  const int own = c * CL;
  const int w_begin = (c == 0) ? 0 : own - CL;
  const int send = own + CL;

  if (lane < T)
    dpL[cur] = (c == 0) ? ((cur == START) ? 0.f : -100000.f) : 0.f;
  asm volatile("" ::: "memory");

  unsigned short q0 = eb[w_begin * T];
  unsigned short q1 = eb[(w_begin + 1 < send ? w_begin + 1 : send - 1) * T];
  unsigned short q2 = eb[(w_begin + 2 < send ? w_begin + 2 : send - 1) * T];
  unsigned short q3 = eb[(w_begin + 3 < send ? w_begin + 3 : send - 1) * T];

  float aVal = 0.f, bVal = 0.f;
  if (mode == 0) {
    for (int s = w_begin; s < send; ++s) {
      const int np = (s + 4 < send) ? s + 4 : send - 1;
      const unsigned short nq = eb[np * T];
      const float nd = astep(bf2f(q0), tr, dpL, cur, h);
      if (lane == 0) {
        if (s == own - 1) aVal = nd;
        if (s == send - 1) bVal = nd;
      }
      q0 = q1; q1 = q2; q2 = q3; q3 = nq;
    }
    if (lane == 0) { aA[b * CH + c] = aVal; bA[b * CH + c] = bVal; }
    if (c == CH - 1) {
      asm volatile("" ::: "memory");
      const float v = (lane < T) ? dpL[lane] + trans[END * T + lane] : -3.0e38f;
      float mx = v;
#pragma unroll
      for (int o = 32; o >= 1; o >>= 1) mx = fmaxf(mx, __shfl_xor(mx, o));
      float sm = (lane < T) ? __expf(v - mx) : 0.f;
#pragma unroll
      for (int o = 32; o >= 1; o >>= 1) sm += __shfl_xor(sm, o);
      if (lane == 0) finA[b] = mx + __logf(sm);
    }
  } else {
    unsigned char* bpb = bpG + (size_t)b * S * T;
    for (int s = w_begin; s < send; ++s) {
      const int np = (s + 4 < send) ? s + 4 : send - 1;
      const unsigned short nq = eb[np * T];
      float best; int arg;
      vstep(bf2f(q0), tr, dpL, cur, h, best, arg);
      if (h == 0 && s >= own) bpb[s * T + cur] = (unsigned char)arg;
      if (lane == 0) {
        if (s == own - 1) aVal = best;
        if (s == send - 1) bVal = best;
      }
      q0 = q1; q1 = q2; q2 = q3; q3 = nq;
    }
    if (lane == 0) { aV[b * CH + c] = aVal; bV[b * CH + c] = bVal; }
    if (c == CH - 1) {
      asm volatile("" ::: "memory");
      float v = (lane < T) ? dpL[lane] + trans[END * T + lane] : -3.0e38f;
      int a = lane;
#pragma unroll
      for (int o = 32; o >= 1; o >>= 1) {
        const float ov = __shfl_xor(v, o);
        const int oa = __shfl_xor(a, o);
        if (ov > v || (ov == v && oa < a)) { v = ov; a = oa; }
      }
      if (lane == 0) { finV[b] = v; tagV[b] = a; }
    }
  }
}

// ---------------------------------------------------------------------------
// Kernel 3: per-batch assembly. 256 threads now: jump-table passes and
// fills parallelize 4x; wave-0 does gold/telescoping; logic unchanged.
// ---------------------------------------------------------------------------
__global__ __launch_bounds__(256) void crf_final(
    const unsigned short* __restrict__ emitb, const int* __restrict__ labels,
    const float* __restrict__ trans,
    const float* __restrict__ aA, const float* __restrict__ bA,
    const float* __restrict__ finA,
    const float* __restrict__ aV, const float* __restrict__ bV,
    const float* __restrict__ finV, const int* __restrict__ tagV,
    const unsigned char* __restrict__ bpG, float* __restrict__ out) {
  __shared__ __align__(16) unsigned char bp[S * T];
  __shared__ unsigned char jA[S * T];
  __shared__ unsigned char jB[S * T];
  __shared__ unsigned char pathb[S];
  __shared__ int anch[64];
  const int tid = threadIdx.x;
  const int b = blockIdx.x;

  {
    const int4* src = (const int4*)(bpG + (size_t)b * S * T);
    int4* dst = (int4*)bp;
    for (int i = tid; i < S * T / 16; i += 256) dst[i] = src[i];
  }

  if (tid < 64) {
    const int lane = tid;
    float g = 0.f;
    for (int s = lane; s < S; s += 64) {
      const int cl = labels[s * B + b];
      const int pl = (s == 0) ? START : labels[(s - 1) * B + b];
      g += trans[cl * T + pl] + bf2f(emitb[(size_t)b * S * T + s * T + cl]);
    }
    if (lane == 63) g += trans[END * T + labels[(S - 1) * B + b]];
#pragma unroll
    for (int o = 32; o >= 1; o >>= 1) g += __shfl_xor(g, o);

    float tb = 0.f, ta = 0.f, vb = 0.f, va = 0.f;
    if (lane < CH - 1) tb = bA[b * CH + lane];
    if (lane >= 1 && lane < CH) ta = aA[b * CH + lane];
    if (lane < CH - 1) vb = bV[b * CH + lane];
    if (lane >= 1 && lane < CH) va = aV[b * CH + lane];
    float dA = tb - ta, dV = vb - va;
#pragma unroll
    for (int o = 32; o >= 1; o >>= 1) {
      dA += __shfl_xor(dA, o);
      dV += __shfl_xor(dV, o);
    }
    if (lane == 0) {
      out[b] = (finA[b] + dA) - g;         // nll
      out[64 + 32768 + b] = finV[b] + dV;  // best score
    }
  }
  __syncthreads();

  // pointer-doubling backtrace (r4-validated), 256-thread strides
  for (int idx = tid; idx < S * T; idx += 256) {
    const int s = idx >> 5;
    if (s >= 1) jA[idx] = bp[(s - 1) * T + bp[idx]];
  }
  __syncthreads();
  for (int idx = tid; idx < S * T; idx += 256) {
    const int s = idx >> 5;
    if (s >= 3) jB[idx] = jA[(s - 2) * T + jA[idx]];
  }
  __syncthreads();
  for (int idx = tid; idx < S * T; idx += 256) {
    const int s = idx >> 5;
    if (s >= 7) jA[idx] = jB[(s - 4) * T + jB[idx]];
  }
  __syncthreads();
  if (tid == 0) {
    int t = tagV[b];
    anch[0] = t;
    for (int j = 1; j < 64; ++j) {
      t = jA[(511 - 8 * (j - 1)) * T + t];
      anch[j] = t;
    }
  }
  __syncthreads();
  if (tid < 64) {
    int t = anch[tid];
    const int s0 = 511 - 8 * tid;
    pathb[s0] = (unsigned char)t;
#pragma unroll
    for (int k = 1; k < 8; ++k) {
      t = bp[(s0 - k + 1) * T + t];
      pathb[s0 - k] = (unsigned char)t;
    }
  }
  __syncthreads();
  for (int i = tid; i < S; i += 256) out[64 + b * S + i] = (float)pathb[i];
}

// ---------------------------------------------------------------------------
extern "C" void kernel_launch(void* const* d_in, const int* in_sizes, int n_in,
                              void* d_out, int out_size, void* d_ws,
                              size_t ws_size, hipStream_t stream) {
  const float* emb = (const float*)d_in[0];
  const int* labels = (const int*)d_in[1];
  const float* W = (const float*)d_in[2];
  const float* bias = (const float*)d_in[3];
  const float* trans = (const float*)d_in[4];
  float* out = (float*)d_out;

  char* p = (char*)d_ws;
  unsigned short* emitb = (unsigned short*)p;  // 2 MiB
  p += (size_t)B * S * T * sizeof(unsigned short);
  unsigned char* bpG = (unsigned char*)p;      // 1 MiB
  p += (size_t)B * S * T;
  float* aA = (float*)p; p += B * CH * sizeof(float);
  float* bA = (float*)p; p += B * CH * sizeof(float);
  float* aV = (float*)p; p += B * CH * sizeof(float);
  float* bV = (float*)p; p += B * CH * sizeof(float);
  float* finA = (float*)p; p += B * sizeof(float);
  float* finV = (float*)p; p += B * sizeof(float);
  int* tagV = (int*)p; p += B * sizeof(int);
  unsigned short* wfrag = (unsigned short*)p;  // 48 KiB (24*2*64*8 shorts)

  wprep<<<12, 256, 0, stream>>>(W, wfrag);
  emit_mfma<<<512, 256, 0, stream>>>(emb, wfrag, bias, emitb);
  crf_chunk<<<2 * CH * B, 64, 0, stream>>>(emitb, trans, aA, bA, finA, aV, bV,
                                           finV, tagV, bpG);
  crf_final<<<B, 256, 0, stream>>>(emitb, labels, trans, aA, bA, finA, aV, bV,
                                   finV, tagV, bpG, out);
}